// Round 7
// baseline (221.567 us; speedup 1.0000x reference)
//
#include <hip/hip_runtime.h>
#include <math.h>

#define NTOK 198
#define CCH  192
#define DIMV 8

typedef float vf4 __attribute__((ext_vector_type(4)));  // clang-native for nontemporal

__device__ __forceinline__ float qgelu(float v) {
    return v / (1.0f + __expf(-1.702f * v));  // x * sigmoid(1.702 x)
}

// Fully fused: down-proj + qgelu -> conv3x3 + qgelu -> up-proj.
// One block per batch element, 512 threads (8 waves). d lives only in LDS.
__global__ __launch_bounds__(512, 4) void convpass_fused(
    const float* __restrict__ x,       // [B,198,192]
    const float* __restrict__ w_down,  // [8,192]
    const float* __restrict__ b_down,  // [8]
    const float* __restrict__ conv_w,  // [8,8,3,3]
    const float* __restrict__ conv_b,  // [8]
    const float* __restrict__ w_up,    // [192,8]
    const float* __restrict__ b_up,    // [192]
    float* __restrict__ out)           // [B,198,192]
{
    const int b   = blockIdx.x;
    const int tid = threadIdx.x;

    __shared__ float s_w[8 * CCH];    // w_down
    __shared__ float s_d[NTOK * 9];   // stride 9 -> conflict-free conv reads
    __shared__ float s_d2[NTOK * 8];  // conv output, stride 8
    __shared__ float s_cw[576];       // conv weights transposed: [kk][i][o]
    __shared__ float s_cb[8];

    // ---- stage w_down (+ conv weights, they're tiny) ----
    for (int t = tid; t < 8 * CCH; t += 512) s_w[t] = w_down[t];
    for (int t = tid; t < 576; t += 512) {
        const int kk = t >> 6, rem = t & 63, i = rem >> 3, o = rem & 7;
        s_cw[t] = conv_w[(o * 8 + i) * 9 + kk];
    }
    if (tid < 8) s_cb[tid] = conv_b[tid];
    __syncthreads();

    // ================= Phase A: d = qgelu(x @ w_down^T + b_down) -> s_d =================
    // wave = 8 tokens x 8 c-chunk lanes; 8 waves x 4 passes cover 198 tokens.
    {
        const int lane  = tid & 63;
        const int wv    = tid >> 6;       // wave 0..7
        const int t_sub = lane >> 3;      // token-slot 0..7
        const int k     = lane & 7;       // c-chunk (24 floats)
        const float bd  = b_down[k];
        const float* xb = x + (size_t)b * NTOK * CCH;

        #pragma unroll 1
        for (int p = 0; p < 4; ++p) {
            const int n = p * 64 + wv * 8 + t_sub;
            const bool valid = (n < NTOK);
            const int nn = valid ? n : (NTOK - 1);  // safe addr for masked lanes
            const float* xr = xb + (size_t)nn * CCH + k * 24;

            float4 xa[6];
            #pragma unroll
            for (int j = 0; j < 6; ++j) xa[j] = *(const float4*)(xr + 4 * j);

            float acc[8] = {0,0,0,0,0,0,0,0};
            #pragma unroll
            for (int j = 0; j < 6; ++j) {
                #pragma unroll
                for (int dm = 0; dm < 8; ++dm) {
                    // 8 distinct addrs/wave (by k), broadcast x8 -> ~2-way: free
                    const float4 wv4 = *(const float4*)&s_w[dm * CCH + k * 24 + j * 4];
                    acc[dm] += xa[j].x * wv4.x + xa[j].y * wv4.y
                             + xa[j].z * wv4.z + xa[j].w * wv4.w;
                }
            }
            float outv = 0.f;
            #pragma unroll
            for (int dm = 0; dm < 8; ++dm) {
                float v = acc[dm];
                v += __shfl_xor(v, 1); v += __shfl_xor(v, 2); v += __shfl_xor(v, 4);
                outv = (dm == k) ? v : outv;
            }
            if (valid) s_d[n * 9 + k] = qgelu(outv + bd);
        }
    }
    __syncthreads();

    // ================= Phase B: conv3x3 + qgelu -> s_d2 =================
    for (int j = tid; j < NTOK * 8; j += 512) {
        const int n = j >> 3, o = j & 7;
        if (n == 1) {
            s_d2[j] = 0.0f;            // dist token zeroed; qgelu(0)=0
        } else if (n == 0) {           // cls: center tap only
            float acc = s_cb[o];
            #pragma unroll
            for (int i = 0; i < 8; ++i)
                acc += s_d[i] * s_cw[4 * 64 + i * 8 + o];
            s_d2[j] = qgelu(acc);
        } else {
            const int pos = n - 2, h = pos / 14, w = pos % 14;
            float acc = s_cb[o];
            #pragma unroll
            for (int dh = -1; dh <= 1; ++dh) {
                const int hh = h + dh;
                if (hh < 0 || hh > 13) continue;
                #pragma unroll
                for (int dw = -1; dw <= 1; ++dw) {
                    const int ww = w + dw;
                    if (ww < 0 || ww > 13) continue;
                    const int tok = 2 + hh * 14 + ww;
                    const int kk  = (dh + 1) * 3 + (dw + 1);
                    #pragma unroll
                    for (int i = 0; i < 8; ++i)
                        acc += s_d[tok * 9 + i] * s_cw[kk * 64 + i * 8 + o];
                }
            }
            s_d2[j] = qgelu(acc);
        }
    }

    // ---- w_up -> registers (global loads issued before the barrier; independent of it)
    const int c4 = tid % 48;
    const int tl = tid / 48;  // 0..10 (tl==10: 32 threads idle in phase C)
    float w_r[4][8];
    #pragma unroll
    for (int cc = 0; cc < 4; ++cc) {
        const float4 wa = *(const float4*)(w_up + (c4 * 4 + cc) * 8);
        const float4 wb = *(const float4*)(w_up + (c4 * 4 + cc) * 8 + 4);
        w_r[cc][0] = wa.x; w_r[cc][1] = wa.y; w_r[cc][2] = wa.z; w_r[cc][3] = wa.w;
        w_r[cc][4] = wb.x; w_r[cc][5] = wb.y; w_r[cc][6] = wb.z; w_r[cc][7] = wb.w;
    }
    const float4 bu = *(const float4*)(b_up + c4 * 4);
    __syncthreads();

    // ================= Phase C: out = d2 @ w_up^T + b_up =================
    if (tl < 10) {
        float* outb = out + (size_t)b * NTOK * CCH;
        #pragma unroll 1
        for (int nr = tl; nr < NTOK; nr += 10) {
            const float4 da = *(const float4*)&s_d2[nr * 8];      // broadcast
            const float4 dv = *(const float4*)&s_d2[nr * 8 + 4];
            float accs[4] = {bu.x, bu.y, bu.z, bu.w};
            #pragma unroll
            for (int cc = 0; cc < 4; ++cc) {
                accs[cc] += da.x * w_r[cc][0] + da.y * w_r[cc][1]
                          + da.z * w_r[cc][2] + da.w * w_r[cc][3]
                          + dv.x * w_r[cc][4] + dv.y * w_r[cc][5]
                          + dv.z * w_r[cc][6] + dv.w * w_r[cc][7];
            }
            const vf4 r = {accs[0], accs[1], accs[2], accs[3]};
            __builtin_nontemporal_store(r, (vf4*)(outb + (size_t)nr * CCH + c4 * 4));
        }
    }
}

extern "C" void kernel_launch(void* const* d_in, const int* in_sizes, int n_in,
                              void* d_out, int out_size, void* d_ws, size_t ws_size,
                              hipStream_t stream) {
    const float* x      = (const float*)d_in[0];
    const float* w_down = (const float*)d_in[1];
    const float* b_down = (const float*)d_in[2];
    const float* conv_w = (const float*)d_in[3];
    const float* conv_b = (const float*)d_in[4];
    const float* w_up   = (const float*)d_in[5];
    const float* b_up   = (const float*)d_in[6];
    float* out = (float*)d_out;

    const int B = in_sizes[0] / (NTOK * CCH);   // 1024
    convpass_fused<<<dim3(B), dim3(512), 0, stream>>>(
        x, w_down, b_down, conv_w, conv_b, w_up, b_up, out);
}

// Round 8
// 86.112 us; speedup vs baseline: 2.5730x; 2.5730x over previous
//
#include <hip/hip_runtime.h>
#include <math.h>

#define NTOK 198
#define CCH  192
#define DIMV 8

typedef float vf4 __attribute__((ext_vector_type(4)));  // clang-native for nontemporal

__device__ __forceinline__ float qgelu(float v) {
    return v / (1.0f + __expf(-1.702f * v));  // x * sigmoid(1.702 x)
}

// Fully fused: down-proj + qgelu -> conv3x3 + qgelu -> up-proj.
// One block per batch element, 512 threads (8 waves). d lives only in LDS.
// launch_bounds(512,2): 128-VGPR cap -> NO SPILL (R7: (512,4) forced 64 VGPR -> scratch
// spill -> +600 MB HBM traffic). 2 blocks/CU = 16 waves/CU, same as spilled version ran.
__global__ __launch_bounds__(512, 2) void convpass_fused(
    const float* __restrict__ x,       // [B,198,192]
    const float* __restrict__ w_down,  // [8,192]
    const float* __restrict__ b_down,  // [8]
    const float* __restrict__ conv_w,  // [8,8,3,3]
    const float* __restrict__ conv_b,  // [8]
    const float* __restrict__ w_up,    // [192,8]
    const float* __restrict__ b_up,    // [192]
    float* __restrict__ out)           // [B,198,192]
{
    const int b   = blockIdx.x;
    const int tid = threadIdx.x;

    __shared__ float s_w[8 * CCH];    // w_down
    __shared__ float s_d[NTOK * 9];   // stride 9 -> conflict-free conv reads
    __shared__ float s_d2[NTOK * 8];  // conv output, stride 8
    __shared__ float s_cw[576];       // conv weights transposed: [kk][i][o]
    __shared__ float s_cb[8];

    // ---- stage w_down (+ conv weights, they're tiny) ----
    for (int t = tid; t < 8 * CCH; t += 512) s_w[t] = w_down[t];
    for (int t = tid; t < 576; t += 512) {
        const int kk = t >> 6, rem = t & 63, i = rem >> 3, o = rem & 7;
        s_cw[t] = conv_w[(o * 8 + i) * 9 + kk];
    }
    if (tid < 8) s_cb[tid] = conv_b[tid];
    __syncthreads();

    // ================= Phase A: d = qgelu(x @ w_down^T + b_down) -> s_d =================
    // wave = 8 tokens x 8 c-chunk lanes; 8 waves x 4 passes cover 198 tokens.
    {
        const int lane  = tid & 63;
        const int wv    = tid >> 6;       // wave 0..7
        const int t_sub = lane >> 3;      // token-slot 0..7
        const int k     = lane & 7;       // c-chunk (24 floats)
        const float bd  = b_down[k];
        const float* xb = x + (size_t)b * NTOK * CCH;

        #pragma unroll 1
        for (int p = 0; p < 4; ++p) {
            const int n = p * 64 + wv * 8 + t_sub;
            const bool valid = (n < NTOK);
            const int nn = valid ? n : (NTOK - 1);  // safe addr for masked lanes
            const float* xr = xb + (size_t)nn * CCH + k * 24;

            float4 xa[6];
            #pragma unroll
            for (int j = 0; j < 6; ++j) xa[j] = *(const float4*)(xr + 4 * j);

            float acc[8] = {0,0,0,0,0,0,0,0};
            #pragma unroll
            for (int j = 0; j < 6; ++j) {
                #pragma unroll
                for (int dm = 0; dm < 8; ++dm) {
                    // 8 distinct addrs/wave (by k), broadcast x8 -> ~2-way: free
                    const float4 wv4 = *(const float4*)&s_w[dm * CCH + k * 24 + j * 4];
                    acc[dm] += xa[j].x * wv4.x + xa[j].y * wv4.y
                             + xa[j].z * wv4.z + xa[j].w * wv4.w;
                }
            }
            float outv = 0.f;
            #pragma unroll
            for (int dm = 0; dm < 8; ++dm) {
                float v = acc[dm];
                v += __shfl_xor(v, 1); v += __shfl_xor(v, 2); v += __shfl_xor(v, 4);
                outv = (dm == k) ? v : outv;
            }
            if (valid) s_d[n * 9 + k] = qgelu(outv + bd);
        }
    }
    __syncthreads();

    // ================= Phase B: conv3x3 + qgelu -> s_d2 =================
    for (int j = tid; j < NTOK * 8; j += 512) {
        const int n = j >> 3, o = j & 7;
        if (n == 1) {
            s_d2[j] = 0.0f;            // dist token zeroed; qgelu(0)=0
        } else if (n == 0) {           // cls: center tap only
            float acc = s_cb[o];
            #pragma unroll
            for (int i = 0; i < 8; ++i)
                acc += s_d[i] * s_cw[4 * 64 + i * 8 + o];
            s_d2[j] = qgelu(acc);
        } else {
            const int pos = n - 2, h = pos / 14, w = pos % 14;
            float acc = s_cb[o];
            #pragma unroll
            for (int dh = -1; dh <= 1; ++dh) {
                const int hh = h + dh;
                if (hh < 0 || hh > 13) continue;
                #pragma unroll
                for (int dw = -1; dw <= 1; ++dw) {
                    const int ww = w + dw;
                    if (ww < 0 || ww > 13) continue;
                    const int tok = 2 + hh * 14 + ww;
                    const int kk  = (dh + 1) * 3 + (dw + 1);
                    #pragma unroll
                    for (int i = 0; i < 8; ++i)
                        acc += s_d[tok * 9 + i] * s_cw[kk * 64 + i * 8 + o];
                }
            }
            s_d2[j] = qgelu(acc);
        }
    }

    // ---- w_up -> registers (global loads issued before the barrier; independent of it)
    const int c4 = tid % 48;
    const int tl = tid / 48;  // 0..10 (tl==10: 32 threads idle in phase C)
    float w_r[4][8];
    #pragma unroll
    for (int cc = 0; cc < 4; ++cc) {
        const float4 wa = *(const float4*)(w_up + (c4 * 4 + cc) * 8);
        const float4 wb = *(const float4*)(w_up + (c4 * 4 + cc) * 8 + 4);
        w_r[cc][0] = wa.x; w_r[cc][1] = wa.y; w_r[cc][2] = wa.z; w_r[cc][3] = wa.w;
        w_r[cc][4] = wb.x; w_r[cc][5] = wb.y; w_r[cc][6] = wb.z; w_r[cc][7] = wb.w;
    }
    const float4 bu = *(const float4*)(b_up + c4 * 4);
    __syncthreads();

    // ================= Phase C: out = d2 @ w_up^T + b_up =================
    if (tl < 10) {
        float* outb = out + (size_t)b * NTOK * CCH;
        #pragma unroll 1
        for (int nr = tl; nr < NTOK; nr += 10) {
            const float4 da = *(const float4*)&s_d2[nr * 8];      // broadcast
            const float4 dv = *(const float4*)&s_d2[nr * 8 + 4];
            float accs[4] = {bu.x, bu.y, bu.z, bu.w};
            #pragma unroll
            for (int cc = 0; cc < 4; ++cc) {
                accs[cc] += da.x * w_r[cc][0] + da.y * w_r[cc][1]
                          + da.z * w_r[cc][2] + da.w * w_r[cc][3]
                          + dv.x * w_r[cc][4] + dv.y * w_r[cc][5]
                          + dv.z * w_r[cc][6] + dv.w * w_r[cc][7];
            }
            const vf4 r = {accs[0], accs[1], accs[2], accs[3]};
            __builtin_nontemporal_store(r, (vf4*)(outb + (size_t)nr * CCH + c4 * 4));
        }
    }
}

extern "C" void kernel_launch(void* const* d_in, const int* in_sizes, int n_in,
                              void* d_out, int out_size, void* d_ws, size_t ws_size,
                              hipStream_t stream) {
    const float* x      = (const float*)d_in[0];
    const float* w_down = (const float*)d_in[1];
    const float* b_down = (const float*)d_in[2];
    const float* conv_w = (const float*)d_in[3];
    const float* conv_b = (const float*)d_in[4];
    const float* w_up   = (const float*)d_in[5];
    const float* b_up   = (const float*)d_in[6];
    float* out = (float*)d_out;

    const int B = in_sizes[0] / (NTOK * CCH);   // 1024
    convpass_fused<<<dim3(B), dim3(512), 0, stream>>>(
        x, w_down, b_down, conv_w, conv_b, w_up, b_up, out);
}